// Round 15
// baseline (1381.551 us; speedup 1.0000x reference)
//
#include <hip/hip_runtime.h>
#include <cstdint>
#include <cstddef>

#define DEVINL __device__ __forceinline__

typedef __attribute__((ext_vector_type(8))) short bf16x8;
typedef __attribute__((ext_vector_type(4))) float f32x4;
typedef __attribute__((ext_vector_type(4))) unsigned short u16x4;
typedef __attribute__((ext_vector_type(4))) unsigned int u32x4;

// ---------- workspace layout ----------
static constexpr size_t OFF_XB   = 0;                              // x bf16 [32768][1024]
static constexpr size_t OFF_WHT  = OFF_XB  + (size_t)32768*1024*2; // Wh^T bf16 [4096][1024]
static constexpr size_t OFF_WXT  = OFF_WHT + (size_t)4096*1024*2;  // Wx^T bf16 [4096][1024]
static constexpr size_t OFF_WCT  = OFF_WXT + (size_t)4096*1024*2;  // Wc^T bf16 [1024][1024]
static constexpr size_t OFF_BIAS = OFF_WCT + (size_t)1024*1024*2;  // bias_all f32 [4096]
static constexpr size_t OFF_XW   = OFF_BIAS + 4096*4;              // XW bf16 [32768][4096]
static constexpr size_t OFF_H    = OFF_XW  + (size_t)32768*4096*2; // h bf16 [32768][1024]
static constexpr size_t OFF_CB   = OFF_H   + (size_t)32768*1024*2; // cell bf16 x2 [128][1024]
static constexpr size_t OFF_BAR  = OFF_CB  + (size_t)2*128*1024*2; // barrier lines, 32 KB
static constexpr size_t WS_NEEDED = OFF_BAR + 32768;

// ---------- helpers ----------
DEVINL unsigned short f2b(float f) {
  union { float f; unsigned u; } v; v.f = f;
  unsigned r = (v.u + 0x7FFFu + ((v.u >> 16) & 1u)) >> 16;  // RNE
  return (unsigned short)r;
}
DEVINL float b2f(unsigned short h) {
  union { unsigned u; float f; } v; v.u = ((unsigned)h) << 16;
  return v.f;
}
DEVINL float sigmoidf_(float x) { return 1.0f / (1.0f + __expf(-x)); }
DEVINL float tanhf_(float x) { float e = __expf(2.0f * x); return 1.0f - 2.0f / (e + 1.0f); }
DEVINL f32x4 MFMA(bf16x8 a, bf16x8 b, f32x4 c) {
  return __builtin_amdgcn_mfma_f32_16x16x32_bf16(a, b, c, 0, 0, 0);
}
DEVINL void gload16(const void* g, void* l) {
  __builtin_amdgcn_global_load_lds(
      (const __attribute__((address_space(1))) void*)g,
      (__attribute__((address_space(3))) void*)l, 16, 0, 0);
}

// ---------- conversions ----------
__global__ void cvt_x_kernel(const float* __restrict__ x, unsigned short* __restrict__ xb) {
  size_t i = ((size_t)blockIdx.x * 256 + threadIdx.x) * 4;
  float4 v = *(const float4*)(x + i);
  u16x4 o; o.x = f2b(v.x); o.y = f2b(v.y); o.z = f2b(v.z); o.w = f2b(v.w);
  *(u16x4*)(xb + i) = o;
}

// coalesced transpose-convert via 64x64 LDS tile (proven r8)
__global__ __launch_bounds__(256)
void cvt_w_kernel(const float* __restrict__ Wf, const float* __restrict__ Wi1,
                  const float* __restrict__ Wi2, const float* __restrict__ Wo,
                  unsigned short* __restrict__ WhT, unsigned short* __restrict__ WxT) {
  __shared__ float tile[64][65];
  const int bid = blockIdx.x;          // 16 jt x 16 kt x 4 g = 1024 blocks
  const int g  = bid & 3;
  const int kt = (bid >> 2) & 15;
  const int jt = bid >> 6;
  const float* W = (g == 0) ? Wf : (g == 1) ? Wi1 : (g == 2) ? Wi2 : Wo;
  const int tid = threadIdx.x;
  const int jj  = tid & 63;
  const int kr  = tid >> 6;            // 0..3

  for (int h = 0; h < 2; ++h) {
    const float* Wb = W + (size_t)(h ? 1024 : 0) * 1024;
#pragma unroll
    for (int i = 0; i < 16; ++i) {
      int kl = i * 4 + kr;
      tile[kl][jj] = Wb[(size_t)(kt * 64 + kl) * 1024 + jt * 64 + jj];
    }
    __syncthreads();
    unsigned short* Out = h ? WxT : WhT;
    unsigned short* op  = Out + (size_t)(4 * (jt * 64 + jj) + g) * 1024 + kt * 64 + kr * 16;
#pragma unroll
    for (int q = 0; q < 4; ++q) {
      u16x4 v;
#pragma unroll
      for (int e = 0; e < 4; ++e)
        ((unsigned short*)&v)[e] = f2b(tile[kr * 16 + q * 4 + e][jj]);
      *(u16x4*)(op + q * 4) = v;
    }
    __syncthreads();
  }
}

__global__ void bias_kernel(const float* __restrict__ bf_, const float* __restrict__ bi1,
                            const float* __restrict__ bi2, const float* __restrict__ bo,
                            float* __restrict__ biasAll) {
  int gc = blockIdx.x * 256 + threadIdx.x;   // 4096
  int j = gc >> 2, g = gc & 3;
  const float* bb = (g == 0) ? bf_ : (g == 1) ? bi1 : (g == 2) ? bi2 : bo;
  biasAll[gc] = bb[j];
}

__global__ void cvt_wc_kernel(const float* __restrict__ Wc, unsigned short* __restrict__ WcT) {
  int idx = blockIdx.x * 256 + threadIdx.x;   // 1024*1024 total
  int k = idx & 1023, n = idx >> 10;
  WcT[idx] = f2b(Wc[(size_t)k * 1024 + n]);
}

// ---------- 256x256 pipelined bf16 GEMM (r12-proven) ----------
template<bool OUT_F32>
__global__ __launch_bounds__(512, 2)
void gemm_bt(const unsigned short* __restrict__ A,
             const unsigned short* __restrict__ Bt,
             const float* __restrict__ bias,
             void* __restrict__ C,
             int M, int N, int K) {
  __shared__ char sT[4][32768];        // per buf: A[256][32] @0, B[256][32] @16384
  const int tid  = threadIdx.x;
  const int lane = tid & 63;
  const int wid  = tid >> 6;
  const int wm   = (wid >> 2) * 128;
  const int wn   = (wid & 3) * 64;

  const int nwg = gridDim.x * gridDim.y;
  const int lin = blockIdx.y * gridDim.x + blockIdx.x;
  const int cpx = nwg >> 3;
  const int swz = (lin & 7) * cpx + (lin >> 3);
  const int m0  = (swz / gridDim.x) * 256;
  const int n0  = (swz % gridDim.x) * 256;

  const int nt = K >> 5;

  f32x4 acc[8][4];
#pragma unroll
  for (int i = 0; i < 8; ++i)
#pragma unroll
    for (int j = 0; j < 4; ++j) acc[i][j] = (f32x4){0.f, 0.f, 0.f, 0.f};

  auto stageA = [&](int kt, int buf) {
#pragma unroll
    for (int l = 0; l < 2; ++l) {
      int s = l * 512 + tid;
      int r = s >> 2, c = s & 3;
      int cg = c ^ ((r >> 1) & 3);
      gload16(A + (size_t)(m0 + r) * K + kt * 32 + cg * 8, sT[buf] + s * 16);
    }
  };
  auto stageB = [&](int kt, int buf) {
#pragma unroll
    for (int l = 0; l < 2; ++l) {
      int s = l * 512 + tid;
      int r = s >> 2, c = s & 3;
      int cg = c ^ ((r >> 1) & 3);
      gload16(Bt + (size_t)(n0 + r) * K + kt * 32 + cg * 8, sT[buf] + 16384 + s * 16);
    }
  };

  stageA(0, 0); stageB(0, 0);
  stageA(1, 1); stageB(1, 1);
  stageA(2, 2); stageB(2, 2);
  asm volatile("s_waitcnt vmcnt(8)" ::: "memory");
  __builtin_amdgcn_s_barrier();

  const int ch = lane >> 4;

#pragma unroll 1
  for (int g = 0; g < nt; ++g) {
    const int rb = g & 3;
    const char* ab = sT[rb];
    const char* bb = sT[rb] + 16384;

    bf16x8 bv[4], av[4];
#pragma unroll
    for (int ni = 0; ni < 4; ++ni) {
      int col = wn + ni * 16 + (lane & 15);
      bv[ni] = *(const bf16x8*)(bb + col * 64 + ((ch ^ ((col >> 1) & 3)) << 4));
    }
#pragma unroll
    for (int mi = 0; mi < 4; ++mi) {
      int row = wm + mi * 16 + (lane & 15);
      av[mi] = *(const bf16x8*)(ab + row * 64 + ((ch ^ ((row >> 1) & 3)) << 4));
    }
    if (g + 3 < nt) stageA(g + 3, (g + 3) & 3);
    __builtin_amdgcn_s_barrier();
    __builtin_amdgcn_s_setprio(1);
#pragma unroll
    for (int mi = 0; mi < 4; ++mi)
#pragma unroll
      for (int ni = 0; ni < 4; ++ni)
        acc[mi][ni] = MFMA(av[mi], bv[ni], acc[mi][ni]);
    __builtin_amdgcn_s_setprio(0);
    __builtin_amdgcn_s_barrier();

#pragma unroll
    for (int mi = 0; mi < 4; ++mi) {
      int row = wm + 64 + mi * 16 + (lane & 15);
      av[mi] = *(const bf16x8*)(ab + row * 64 + ((ch ^ ((row >> 1) & 3)) << 4));
    }
    if (g + 3 < nt) stageB(g + 3, (g + 3) & 3);
    __builtin_amdgcn_s_barrier();
    __builtin_amdgcn_s_setprio(1);
#pragma unroll
    for (int mi = 0; mi < 4; ++mi)
#pragma unroll
      for (int ni = 0; ni < 4; ++ni)
        acc[mi + 4][ni] = MFMA(av[mi], bv[ni], acc[mi + 4][ni]);
    __builtin_amdgcn_s_setprio(0);

    if (g <= nt - 4)      asm volatile("s_waitcnt vmcnt(8)" ::: "memory");
    else if (g == nt - 3) asm volatile("s_waitcnt vmcnt(4)" ::: "memory");
    else if (g == nt - 2) asm volatile("s_waitcnt vmcnt(0)" ::: "memory");
    __builtin_amdgcn_s_barrier();
  }

#pragma unroll
  for (int mi = 0; mi < 8; ++mi)
#pragma unroll
    for (int ni = 0; ni < 4; ++ni)
#pragma unroll
      for (int r = 0; r < 4; ++r) {
        int row = m0 + wm + mi * 16 + (lane >> 4) * 4 + r;
        int col = n0 + wn + ni * 16 + (lane & 15);
        float v = acc[mi][ni][r] + bias[col];
        if (OUT_F32) ((float*)C)[(size_t)row * N + col] = v;
        else ((unsigned short*)C)[(size_t)row * N + col] = f2b(v);
      }
}

// ---------- persistent recurrence v15: r14 + in-wave gate transpose ----------
// Identical envelope/protocol to r14 (924us): 256 WGs x 512 thr, 8 row-groups
// x 32 WGs, MALL protocol, 2-level tree barrier, deferred-H, XW prefetch.
// Changes (intra-step only, same arithmetic):
//  (1) sP LDS redistribute + its __syncthreads DELETED. The 4 gates of cell
//      q live in the 4 adjacent lanes of a quad (gate g=r0&3, cell q=r0>>2)
//      at acc[g]; a 4x4 in-quad transpose (3 __shfl + cndmask selects) hands
//      each lane all 4 gates of one (row, cell). Lane (ch,q,g) owns row
//      ch*4+g, cell col nh*4+q. Verified: round d pulls sender (q,(g+d)&3)'s
//      acc[(s-d)&3]; gate gi arrives in val[(gi-g)&3].
//  (2) accumulator split into 4 independent MFMA chains (ks mod 4), summed
//      at the end (dependent-latency 32L -> 8L).
__global__ __launch_bounds__(512, 2)
void lstm_persist(const unsigned short* __restrict__ WhT,  // [4096][1024] bf16
                  const unsigned short* __restrict__ XW,   // [32768][4096] bf16
                  unsigned short* __restrict__ H,          // [32768][1024] bf16
                  unsigned short* __restrict__ cB0,        // [128][1024] bf16
                  unsigned short* __restrict__ cB1,
                  float* __restrict__ cellOut,             // [128][1024] f32
                  unsigned* __restrict__ bar) {
  __shared__ __align__(16) char sA[16 * 2064];   // 33 KB A-tile, padded stride

  const int tid  = threadIdx.x;
  const int lane = tid & 63;
  const int nh   = tid >> 6;       // wave id = n-tile 0..7
  const int wgid = blockIdx.x;
  const int mq   = wgid & 7;       // row-group (16 rows)
  const int cs   = wgid >> 3;      // col slice 0..31 (128 gate-cols)
  const int sg   = cs >> 2;        // subgroup 0..7 (4 WGs each)

  // barrier lines (256B spacing): qc 0..511, qf 512..1023, gcnt 1024..5119
  unsigned* qc   = bar + mq * 64;
  unsigned* qf   = bar + 512 + mq * 64;
  unsigned* gcnt = bar + 1024 + (mq * 8 + sg) * 64;

  const int r0 = lane & 15;        // row within m-tile / col within n-tile
  const int ch = lane >> 4;        // 16B chunk id within K-slice
  const int qq = r0 >> 2;          // quad index = cell within wave's 4
  const int g  = r0 & 3;           // gate index

  // ---- Wh fragments in registers: volatile loads (non-remat), 128 regs ----
  bf16x8 bfr[32];
  {
    const unsigned short* bp = WhT + (size_t)(cs * 128 + nh * 16 + r0) * 1024 + ch * 8;
#pragma unroll
    for (int ks = 0; ks < 32; ++ks)
      bfr[ks] = *(const volatile bf16x8*)(bp + ks * 32);
  }

  // ---- per-lane cell ownership: row ch*4+g, cell col nh*4+qq ----
  const int browg = mq * 16 + ch * 4 + g;      // global batch row
  const int ccol  = cs * 32 + nh * 4 + qq;     // global cell col
  float cf = 0.f;

  const unsigned short* xwp = XW + (size_t)browg * 256 * 4096 + ccol * 4;
  // u32 store pointers (qq-even lanes store cols {ccol, ccol+1})
  unsigned* c0p = (unsigned*)(cB0 + (size_t)browg * 1024 + ccol);
  unsigned* c1p = (unsigned*)(cB1 + (size_t)browg * 1024 + ccol);
  unsigned* hp  = (unsigned*)(H + (size_t)browg * 256 * 1024 + ccol);

  // staging geometry: thread covers rows {4it+strow}, 16B chunk stcc
  const int strow = tid >> 7;            // 0..3
  const int stcc  = tid & 127;           // 0..127

  // prologue: xw for t=0
  u16x4 xw = *(const u16x4*)(xwp);

  for (int t = 0; t < 256; ++t) {
    const unsigned short* cinq = ((t & 1) ? cB1 : cB0) + (size_t)mq * 16 * 1024;

    // ---- stage A-tile [16][1024] bf16: coherent loads -> regs -> LDS ----
    u32x4 st[4];
#pragma unroll
    for (int it = 0; it < 4; ++it) {
      const void* p = cinq + (size_t)(it * 4 + strow) * 1024 + stcc * 8;
      asm volatile("global_load_dwordx4 %0, %1, off sc0 sc1"
                   : "=&v"(st[it]) : "v"(p) : "memory");
    }
    asm volatile("s_waitcnt vmcnt(0)" ::: "memory");
    __builtin_amdgcn_sched_barrier(0);
#pragma unroll
    for (int it = 0; it < 4; ++it) {
      int r = it * 4 + strow;
      *(u32x4*)&sA[r * 2064 + stcc * 16] = st[it];
    }
    __syncthreads();   // sA ready

    // ---- GEMM: one 16x16 tile per wave, K=1024; 4 independent chains ----
    f32x4 aA = (f32x4){0.f, 0.f, 0.f, 0.f};
    f32x4 aB = (f32x4){0.f, 0.f, 0.f, 0.f};
    f32x4 aC = (f32x4){0.f, 0.f, 0.f, 0.f};
    f32x4 aD = (f32x4){0.f, 0.f, 0.f, 0.f};
#pragma unroll
    for (int ks = 0; ks < 32; ks += 4) {
      aA = MFMA(*(const bf16x8*)&sA[r0 * 2064 + (ch + ks * 4) * 16],       bfr[ks],     aA);
      aB = MFMA(*(const bf16x8*)&sA[r0 * 2064 + (ch + (ks + 1) * 4) * 16], bfr[ks + 1], aB);
      aC = MFMA(*(const bf16x8*)&sA[r0 * 2064 + (ch + (ks + 2) * 4) * 16], bfr[ks + 2], aC);
      aD = MFMA(*(const bf16x8*)&sA[r0 * 2064 + (ch + (ks + 3) * 4) * 16], bfr[ks + 3], aD);
    }
    f32x4 acc = (aA + aB) + (aC + aD);

    // ---- in-wave 4x4 quad transpose: gather this lane's 4 gate preacts ----
    float a0 = acc[0], a1 = acc[1], a2 = acc[2], a3 = acc[3];
    float v0 = (g == 0) ? a0 : (g == 1) ? a1 : (g == 2) ? a2 : a3;   // acc[g]
    float p1 = (g == 0) ? a3 : (g == 1) ? a0 : (g == 2) ? a1 : a2;   // acc[(g-1)&3]
    float p2 = (g == 0) ? a2 : (g == 1) ? a3 : (g == 2) ? a0 : a1;   // acc[(g-2)&3]
    float p3 = (g == 0) ? a1 : (g == 1) ? a2 : (g == 2) ? a3 : a0;   // acc[(g-3)&3]
    const int qb = lane & ~3;
    float v1 = __shfl(p1, qb | ((g + 1) & 3));
    float v2 = __shfl(p2, qb | ((g + 2) & 3));
    float v3 = __shfl(p3, qb | ((g + 3) & 3));
    // gate gi sits in val[(gi-g)&3]
    float pf = (g == 0) ? v0 : (g == 1) ? v3 : (g == 2) ? v2 : v1;
    float pi = (g == 0) ? v1 : (g == 1) ? v0 : (g == 2) ? v3 : v2;
    float pg = (g == 0) ? v2 : (g == 1) ? v1 : (g == 2) ? v0 : v3;
    float po = (g == 0) ? v3 : (g == 1) ? v2 : (g == 2) ? v1 : v0;

    // ---- critical-path elementwise: c2 only (3 transcendentals) ----
    pf += b2f((unsigned short)xw[0]);
    pi += b2f((unsigned short)xw[1]);
    pg += b2f((unsigned short)xw[2]);
    float f  = sigmoidf_(pf), i1 = sigmoidf_(pi), gg2 = tanhf_(pg);
    float c2 = cf * f + i1 * gg2; cf = c2;

    // cell: pack adjacent cols via shfl, qq-even lanes agent-store u32 to MALL
    unsigned cl  = f2b(c2);
    unsigned chi = __shfl_down(cl, 4);
    if (!(qq & 1))
      __hip_atomic_store((t & 1) ? c0p : c1p, cl | (chi << 16),
                         __ATOMIC_RELAXED, __HIP_MEMORY_SCOPE_AGENT);

    // ---- drain: all cell stores at MALL, then signal ----
    __syncthreads();
    if (tid == 0) {
      unsigned tgt1 = 4u * (unsigned)(t + 1);
      unsigned tgt2 = 8u * (unsigned)(t + 1);
      unsigned n = __hip_atomic_fetch_add(gcnt, 1u, __ATOMIC_RELAXED,
                                          __HIP_MEMORY_SCOPE_AGENT);
      if (n == tgt1 - 1u) {
        unsigned m = __hip_atomic_fetch_add(qc, 1u, __ATOMIC_RELAXED,
                                            __HIP_MEMORY_SCOPE_AGENT);
        if (m == tgt2 - 1u)
          __hip_atomic_store(qf, (unsigned)(t + 1),
                             __ATOMIC_RELAXED, __HIP_MEMORY_SCOPE_AGENT);
      }
    }

    // ---- spin-window work: h + H store (not needed by consumers) ----
    {
      float poa = po + b2f((unsigned short)xw[3]);
      float h   = sigmoidf_(poa) * tanhf_(c2);
      unsigned hl = f2b(h);
      unsigned hh = __shfl_down(hl, 4);
      if (!(qq & 1))
        *(hp + (size_t)t * 512) = hl | (hh << 16);   // u32 ptr: row stride 512 u32
    }
    // prefetch next step's XW row (read-only stream)
    if (t < 255) xw = *(const u16x4*)(xwp + (size_t)(t + 1) * 4096);

    if (tid == 0) {
      while (__hip_atomic_load(qf, __ATOMIC_RELAXED, __HIP_MEMORY_SCOPE_AGENT)
             < (unsigned)(t + 1))
        __builtin_amdgcn_s_sleep(1);
    }
    __syncthreads();   // release
  }

  // final f32 cell state from registers (kernel-end flush covers it)
  cellOut[(size_t)browg * 1024 + ccol] = cf;
}

// ---------- launcher ----------
extern "C" void kernel_launch(void* const* d_in, const int* in_sizes, int n_in,
                              void* d_out, int out_size, void* d_ws, size_t ws_size,
                              hipStream_t stream) {
  const float* x   = (const float*)d_in[0];
  const float* Wf  = (const float*)d_in[1];
  const float* bfv = (const float*)d_in[2];
  const float* Wi1 = (const float*)d_in[3];
  const float* bi1 = (const float*)d_in[4];
  const float* Wi2 = (const float*)d_in[5];
  const float* bi2 = (const float*)d_in[6];
  const float* Wo  = (const float*)d_in[7];
  const float* bo  = (const float*)d_in[8];
  const float* Wc  = (const float*)d_in[9];
  const float* bc  = (const float*)d_in[10];
  float* out = (float*)d_out;

  if (ws_size < WS_NEEDED) return;  // visible failure instead of corruption

  char* ws = (char*)d_ws;
  unsigned short* xb      = (unsigned short*)(ws + OFF_XB);
  unsigned short* WhT     = (unsigned short*)(ws + OFF_WHT);
  unsigned short* WxT     = (unsigned short*)(ws + OFF_WXT);
  unsigned short* WcT     = (unsigned short*)(ws + OFF_WCT);
  float*          biasAll = (float*)(ws + OFF_BIAS);
  unsigned short* XW      = (unsigned short*)(ws + OFF_XW);
  unsigned short* H       = (unsigned short*)(ws + OFF_H);
  unsigned short* cB0     = (unsigned short*)(ws + OFF_CB);
  unsigned short* cB1     = (unsigned short*)(ws + OFF_CB + (size_t)128 * 1024 * 2);
  unsigned*       barLn   = (unsigned*)(ws + OFF_BAR);
  float*          cellOut = out + (size_t)32768 * 1024;

  hipMemsetAsync(cB0, 0, (size_t)128 * 1024 * 2, stream);
  hipMemsetAsync(barLn, 0, 32768, stream);    // reset barrier lines EVERY launch

  cvt_x_kernel <<<32768, 256, 0, stream>>>(x, xb);
  cvt_w_kernel <<< 1024, 256, 0, stream>>>(Wf, Wi1, Wi2, Wo, WhT, WxT);
  bias_kernel  <<<   16, 256, 0, stream>>>(bfv, bi1, bi2, bo, biasAll);
  cvt_wc_kernel<<< 4096, 256, 0, stream>>>(Wc, WcT);

  // XW = x @ Wx_all + biases   (M=32768, N=4096, K=1024), bf16 out, 256^2 tiles
  gemm_bt<false><<<dim3(16, 128), 512, 0, stream>>>(xb, WxT, biasAll, XW, 32768, 4096, 1024);

  // persistent recurrence: 256 WGs x 512 threads (proven envelope), cooperative
  {
    void* args[] = { (void*)&WhT, (void*)&XW, (void*)&H,
                     (void*)&cB0, (void*)&cB1, (void*)&cellOut, (void*)&barLn };
    hipLaunchCooperativeKernel(lstm_persist, dim3(256), dim3(512), args, 0u, stream);
  }

  // output_sequence = h @ Wc + bc  (M=32768, N=1024, K=1024), f32 out
  gemm_bt<true><<<dim3(4, 128), 512, 0, stream>>>(H, WcT, bc, out, 32768, 1024, 1024);
}

// Round 16
// 1349.995 us; speedup vs baseline: 1.0234x; 1.0234x over previous
//
#include <hip/hip_runtime.h>
#include <cstdint>
#include <cstddef>

#define DEVINL __device__ __forceinline__

typedef __attribute__((ext_vector_type(8))) short bf16x8;
typedef __attribute__((ext_vector_type(4))) float f32x4;
typedef __attribute__((ext_vector_type(4))) unsigned short u16x4;
typedef __attribute__((ext_vector_type(4))) unsigned int u32x4;

// ---------- workspace layout ----------
static constexpr size_t OFF_XB   = 0;                              // x bf16 [32768][1024]
static constexpr size_t OFF_WHT  = OFF_XB  + (size_t)32768*1024*2; // Wh^T bf16 [4096][1024]
static constexpr size_t OFF_WXT  = OFF_WHT + (size_t)4096*1024*2;  // Wx^T bf16 [4096][1024]
static constexpr size_t OFF_WCT  = OFF_WXT + (size_t)4096*1024*2;  // Wc^T bf16 [1024][1024]
static constexpr size_t OFF_BIAS = OFF_WCT + (size_t)1024*1024*2;  // bias_all f32 [4096]
static constexpr size_t OFF_XW   = OFF_BIAS + 4096*4;              // XW bf16 [32768][4096]
static constexpr size_t OFF_H    = OFF_XW  + (size_t)32768*4096*2; // h bf16 [32768][1024]
static constexpr size_t OFF_CB   = OFF_H   + (size_t)32768*1024*2; // cell bf16 x2 [128][1024]
static constexpr size_t OFF_BAR  = OFF_CB  + (size_t)2*128*1024*2; // barrier lines, 32 KB
static constexpr size_t WS_NEEDED = OFF_BAR + 32768;

// ---------- helpers ----------
DEVINL unsigned short f2b(float f) {
  union { float f; unsigned u; } v; v.f = f;
  unsigned r = (v.u + 0x7FFFu + ((v.u >> 16) & 1u)) >> 16;  // RNE
  return (unsigned short)r;
}
DEVINL float b2f(unsigned short h) {
  union { unsigned u; float f; } v; v.u = ((unsigned)h) << 16;
  return v.f;
}
DEVINL float sigmoidf_(float x) { return 1.0f / (1.0f + __expf(-x)); }
DEVINL float tanhf_(float x) { float e = __expf(2.0f * x); return 1.0f - 2.0f / (e + 1.0f); }
DEVINL f32x4 MFMA(bf16x8 a, bf16x8 b, f32x4 c) {
  return __builtin_amdgcn_mfma_f32_16x16x32_bf16(a, b, c, 0, 0, 0);
}
DEVINL void gload16(const void* g, void* l) {
  __builtin_amdgcn_global_load_lds(
      (const __attribute__((address_space(1))) void*)g,
      (__attribute__((address_space(3))) void*)l, 16, 0, 0);
}

// ---------- conversions ----------
__global__ void cvt_x_kernel(const float* __restrict__ x, unsigned short* __restrict__ xb) {
  size_t i = ((size_t)blockIdx.x * 256 + threadIdx.x) * 4;
  float4 v = *(const float4*)(x + i);
  u16x4 o; o.x = f2b(v.x); o.y = f2b(v.y); o.z = f2b(v.z); o.w = f2b(v.w);
  *(u16x4*)(xb + i) = o;
}

// coalesced transpose-convert via 64x64 LDS tile (proven r8)
__global__ __launch_bounds__(256)
void cvt_w_kernel(const float* __restrict__ Wf, const float* __restrict__ Wi1,
                  const float* __restrict__ Wi2, const float* __restrict__ Wo,
                  unsigned short* __restrict__ WhT, unsigned short* __restrict__ WxT) {
  __shared__ float tile[64][65];
  const int bid = blockIdx.x;          // 16 jt x 16 kt x 4 g = 1024 blocks
  const int g  = bid & 3;
  const int kt = (bid >> 2) & 15;
  const int jt = bid >> 6;
  const float* W = (g == 0) ? Wf : (g == 1) ? Wi1 : (g == 2) ? Wi2 : Wo;
  const int tid = threadIdx.x;
  const int jj  = tid & 63;
  const int kr  = tid >> 6;            // 0..3

  for (int h = 0; h < 2; ++h) {
    const float* Wb = W + (size_t)(h ? 1024 : 0) * 1024;
#pragma unroll
    for (int i = 0; i < 16; ++i) {
      int kl = i * 4 + kr;
      tile[kl][jj] = Wb[(size_t)(kt * 64 + kl) * 1024 + jt * 64 + jj];
    }
    __syncthreads();
    unsigned short* Out = h ? WxT : WhT;
    unsigned short* op  = Out + (size_t)(4 * (jt * 64 + jj) + g) * 1024 + kt * 64 + kr * 16;
#pragma unroll
    for (int q = 0; q < 4; ++q) {
      u16x4 v;
#pragma unroll
      for (int e = 0; e < 4; ++e)
        ((unsigned short*)&v)[e] = f2b(tile[kr * 16 + q * 4 + e][jj]);
      *(u16x4*)(op + q * 4) = v;
    }
    __syncthreads();
  }
}

__global__ void bias_kernel(const float* __restrict__ bf_, const float* __restrict__ bi1,
                            const float* __restrict__ bi2, const float* __restrict__ bo,
                            float* __restrict__ biasAll) {
  int gc = blockIdx.x * 256 + threadIdx.x;   // 4096
  int j = gc >> 2, g = gc & 3;
  const float* bb = (g == 0) ? bf_ : (g == 1) ? bi1 : (g == 2) ? bi2 : bo;
  biasAll[gc] = bb[j];
}

__global__ void cvt_wc_kernel(const float* __restrict__ Wc, unsigned short* __restrict__ WcT) {
  int idx = blockIdx.x * 256 + threadIdx.x;   // 1024*1024 total
  int k = idx & 1023, n = idx >> 10;
  WcT[idx] = f2b(Wc[(size_t)k * 1024 + n]);
}

// ---------- 256x256 pipelined bf16 GEMM (r12-proven) ----------
template<bool OUT_F32>
__global__ __launch_bounds__(512, 2)
void gemm_bt(const unsigned short* __restrict__ A,
             const unsigned short* __restrict__ Bt,
             const float* __restrict__ bias,
             void* __restrict__ C,
             int M, int N, int K) {
  __shared__ char sT[4][32768];        // per buf: A[256][32] @0, B[256][32] @16384
  const int tid  = threadIdx.x;
  const int lane = tid & 63;
  const int wid  = tid >> 6;
  const int wm   = (wid >> 2) * 128;
  const int wn   = (wid & 3) * 64;

  const int nwg = gridDim.x * gridDim.y;
  const int lin = blockIdx.y * gridDim.x + blockIdx.x;
  const int cpx = nwg >> 3;
  const int swz = (lin & 7) * cpx + (lin >> 3);
  const int m0  = (swz / gridDim.x) * 256;
  const int n0  = (swz % gridDim.x) * 256;

  const int nt = K >> 5;

  f32x4 acc[8][4];
#pragma unroll
  for (int i = 0; i < 8; ++i)
#pragma unroll
    for (int j = 0; j < 4; ++j) acc[i][j] = (f32x4){0.f, 0.f, 0.f, 0.f};

  auto stageA = [&](int kt, int buf) {
#pragma unroll
    for (int l = 0; l < 2; ++l) {
      int s = l * 512 + tid;
      int r = s >> 2, c = s & 3;
      int cg = c ^ ((r >> 1) & 3);
      gload16(A + (size_t)(m0 + r) * K + kt * 32 + cg * 8, sT[buf] + s * 16);
    }
  };
  auto stageB = [&](int kt, int buf) {
#pragma unroll
    for (int l = 0; l < 2; ++l) {
      int s = l * 512 + tid;
      int r = s >> 2, c = s & 3;
      int cg = c ^ ((r >> 1) & 3);
      gload16(Bt + (size_t)(n0 + r) * K + kt * 32 + cg * 8, sT[buf] + 16384 + s * 16);
    }
  };

  stageA(0, 0); stageB(0, 0);
  stageA(1, 1); stageB(1, 1);
  stageA(2, 2); stageB(2, 2);
  asm volatile("s_waitcnt vmcnt(8)" ::: "memory");
  __builtin_amdgcn_s_barrier();

  const int ch = lane >> 4;

#pragma unroll 1
  for (int g = 0; g < nt; ++g) {
    const int rb = g & 3;
    const char* ab = sT[rb];
    const char* bb = sT[rb] + 16384;

    bf16x8 bv[4], av[4];
#pragma unroll
    for (int ni = 0; ni < 4; ++ni) {
      int col = wn + ni * 16 + (lane & 15);
      bv[ni] = *(const bf16x8*)(bb + col * 64 + ((ch ^ ((col >> 1) & 3)) << 4));
    }
#pragma unroll
    for (int mi = 0; mi < 4; ++mi) {
      int row = wm + mi * 16 + (lane & 15);
      av[mi] = *(const bf16x8*)(ab + row * 64 + ((ch ^ ((row >> 1) & 3)) << 4));
    }
    if (g + 3 < nt) stageA(g + 3, (g + 3) & 3);
    __builtin_amdgcn_s_barrier();
    __builtin_amdgcn_s_setprio(1);
#pragma unroll
    for (int mi = 0; mi < 4; ++mi)
#pragma unroll
      for (int ni = 0; ni < 4; ++ni)
        acc[mi][ni] = MFMA(av[mi], bv[ni], acc[mi][ni]);
    __builtin_amdgcn_s_setprio(0);
    __builtin_amdgcn_s_barrier();

#pragma unroll
    for (int mi = 0; mi < 4; ++mi) {
      int row = wm + 64 + mi * 16 + (lane & 15);
      av[mi] = *(const bf16x8*)(ab + row * 64 + ((ch ^ ((row >> 1) & 3)) << 4));
    }
    if (g + 3 < nt) stageB(g + 3, (g + 3) & 3);
    __builtin_amdgcn_s_barrier();
    __builtin_amdgcn_s_setprio(1);
#pragma unroll
    for (int mi = 0; mi < 4; ++mi)
#pragma unroll
      for (int ni = 0; ni < 4; ++ni)
        acc[mi + 4][ni] = MFMA(av[mi], bv[ni], acc[mi + 4][ni]);
    __builtin_amdgcn_s_setprio(0);

    if (g <= nt - 4)      asm volatile("s_waitcnt vmcnt(8)" ::: "memory");
    else if (g == nt - 3) asm volatile("s_waitcnt vmcnt(4)" ::: "memory");
    else if (g == nt - 2) asm volatile("s_waitcnt vmcnt(0)" ::: "memory");
    __builtin_amdgcn_s_barrier();
  }

#pragma unroll
  for (int mi = 0; mi < 8; ++mi)
#pragma unroll
    for (int ni = 0; ni < 4; ++ni)
#pragma unroll
      for (int r = 0; r < 4; ++r) {
        int row = m0 + wm + mi * 16 + (lane >> 4) * 4 + r;
        int col = n0 + wn + ni * 16 + (lane & 15);
        float v = acc[mi][ni][r] + bias[col];
        if (OUT_F32) ((float*)C)[(size_t)row * N + col] = v;
        else ((unsigned short*)C)[(size_t)row * N + col] = f2b(v);
      }
}

// ---------- persistent recurrence v16: r14 + 4-chain MFMA split ----------
// Byte-identical to r14 (924us proven) except the GEMM inner loop: the
// accumulator is split into 4 independent MFMA chains (ks mod 4) summed at
// the end (dependent-chain latency 32L -> 8L). r15's in-wave transpose is
// REVERTED (it scattered the cell/H stores: WRITE_SIZE 134->331 MB, +53us).
// Structure: 256 WGs x 512 thr, 8 row-groups x 32 WGs; MALL protocol (relaxed
// agent-atomic coalesced cell stores, sc0|sc1 asm cell loads, H plain cached);
// 2-level tree barrier (tid0 only); elementwise on all 512 threads (1 cell);
// h + H store deferred into the spin window; XW row prefetched.
__global__ __launch_bounds__(512, 2)
void lstm_persist(const unsigned short* __restrict__ WhT,  // [4096][1024] bf16
                  const unsigned short* __restrict__ XW,   // [32768][4096] bf16
                  unsigned short* __restrict__ H,          // [32768][1024] bf16
                  unsigned short* __restrict__ cB0,        // [128][1024] bf16
                  unsigned short* __restrict__ cB1,
                  float* __restrict__ cellOut,             // [128][1024] f32
                  unsigned* __restrict__ bar) {
  __shared__ __align__(16) char  sA[16 * 2064];   // 33 KB A-tile, padded stride
  __shared__ __align__(16) float sP[16 * 132];    // 8.4 KB preact redistribute

  const int tid  = threadIdx.x;
  const int lane = tid & 63;
  const int nh   = tid >> 6;       // wave id = n-tile 0..7
  const int wgid = blockIdx.x;
  const int mq   = wgid & 7;       // row-group (16 rows)
  const int cs   = wgid >> 3;      // col slice 0..31 (128 gate-cols)
  const int sg   = cs >> 2;        // subgroup 0..7 (4 WGs each)

  // barrier lines (256B spacing): qc 0..511, qf 512..1023, gcnt 1024..5119
  unsigned* qc   = bar + mq * 64;
  unsigned* qf   = bar + 512 + mq * 64;
  unsigned* gcnt = bar + 1024 + (mq * 8 + sg) * 64;

  const int r0 = lane & 15;        // row within m-tile / col within n-tile
  const int ch = lane >> 4;        // 16B chunk id within K-slice

  // ---- Wh fragments in registers: volatile loads (non-remat), 128 regs ----
  bf16x8 bfr[32];
  {
    const unsigned short* bp = WhT + (size_t)(cs * 128 + nh * 16 + r0) * 1024 + ch * 8;
#pragma unroll
    for (int ks = 0; ks < 32; ++ks)
      bfr[ks] = *(const volatile bf16x8*)(bp + ks * 32);
  }

  // ---- per-thread cell ownership: ALL 512 threads, 1 cell each ----
  const int erow  = tid >> 5;            // 0..15 (row within group)
  const int ecol  = tid & 31;            // cell col within slice
  const int browg = mq * 16 + erow;      // global batch row
  float cf = 0.f;

  const unsigned short* xwp = XW + (size_t)browg * 256 * 4096 + cs * 128 + ecol * 4;
  // u32 store pointers (even lanes store cols {ecol, ecol+1})
  unsigned* c0p = (unsigned*)(cB0 + (size_t)browg * 1024 + cs * 32 + ecol);
  unsigned* c1p = (unsigned*)(cB1 + (size_t)browg * 1024 + cs * 32 + ecol);
  unsigned* hp  = (unsigned*)(H + (size_t)browg * 256 * 1024 + cs * 32 + ecol);

  // staging geometry: thread covers rows {4it+strow}, 16B chunk stcc
  const int strow = tid >> 7;            // 0..3
  const int stcc  = tid & 127;           // 0..127

  // prologue: xw for t=0
  u16x4 xw = *(const u16x4*)(xwp);

  for (int t = 0; t < 256; ++t) {
    const unsigned short* cinq = ((t & 1) ? cB1 : cB0) + (size_t)mq * 16 * 1024;

    // ---- stage A-tile [16][1024] bf16: coherent loads -> regs -> LDS ----
    u32x4 st[4];
#pragma unroll
    for (int it = 0; it < 4; ++it) {
      const void* p = cinq + (size_t)(it * 4 + strow) * 1024 + stcc * 8;
      asm volatile("global_load_dwordx4 %0, %1, off sc0 sc1"
                   : "=&v"(st[it]) : "v"(p) : "memory");
    }
    asm volatile("s_waitcnt vmcnt(0)" ::: "memory");
    __builtin_amdgcn_sched_barrier(0);
#pragma unroll
    for (int it = 0; it < 4; ++it) {
      int r = it * 4 + strow;
      *(u32x4*)&sA[r * 2064 + stcc * 16] = st[it];
    }
    __syncthreads();   // sA ready

    // ---- GEMM: one 16x16 tile per wave, K=1024; 4 independent chains ----
    f32x4 aA = (f32x4){0.f, 0.f, 0.f, 0.f};
    f32x4 aB = (f32x4){0.f, 0.f, 0.f, 0.f};
    f32x4 aC = (f32x4){0.f, 0.f, 0.f, 0.f};
    f32x4 aD = (f32x4){0.f, 0.f, 0.f, 0.f};
#pragma unroll
    for (int ks = 0; ks < 32; ks += 4) {
      aA = MFMA(*(const bf16x8*)&sA[r0 * 2064 + (ch + ks * 4) * 16],       bfr[ks],     aA);
      aB = MFMA(*(const bf16x8*)&sA[r0 * 2064 + (ch + (ks + 1) * 4) * 16], bfr[ks + 1], aB);
      aC = MFMA(*(const bf16x8*)&sA[r0 * 2064 + (ch + (ks + 2) * 4) * 16], bfr[ks + 2], aC);
      aD = MFMA(*(const bf16x8*)&sA[r0 * 2064 + (ch + (ks + 3) * 4) * 16], bfr[ks + 3], aD);
    }
    f32x4 acc = (aA + aB) + (aC + aD);

    // ---- redistribute preacts via LDS (r14 layout: coalesced stores) ----
#pragma unroll
    for (int rr = 0; rr < 4; ++rr)
      sP[(ch * 4 + rr) * 132 + nh * 16 + r0] = acc[rr];
    __syncthreads();   // sP ready

    // ---- critical-path elementwise: c2 only (3 transcendentals) ----
    float4 g = *(const float4*)&sP[erow * 132 + ecol * 4];
    float pf = g.x + b2f((unsigned short)xw[0]);
    float pi = g.y + b2f((unsigned short)xw[1]);
    float pg = g.z + b2f((unsigned short)xw[2]);
    float f  = sigmoidf_(pf), i1 = sigmoidf_(pi), gg = tanhf_(pg);
    float c2 = cf * f + i1 * gg; cf = c2;

    // cell: pack adjacent cols via shfl, even lanes agent-store u32 to MALL
    unsigned cl = f2b(c2);
    unsigned chi = __shfl_down(cl, 1);
    if (!(lane & 1))
      __hip_atomic_store((t & 1) ? c0p : c1p, cl | (chi << 16),
                         __ATOMIC_RELAXED, __HIP_MEMORY_SCOPE_AGENT);

    // ---- drain: all cell stores at MALL, then signal ----
    __syncthreads();
    if (tid == 0) {
      unsigned tgt1 = 4u * (unsigned)(t + 1);
      unsigned tgt2 = 8u * (unsigned)(t + 1);
      unsigned n = __hip_atomic_fetch_add(gcnt, 1u, __ATOMIC_RELAXED,
                                          __HIP_MEMORY_SCOPE_AGENT);
      if (n == tgt1 - 1u) {
        unsigned m = __hip_atomic_fetch_add(qc, 1u, __ATOMIC_RELAXED,
                                            __HIP_MEMORY_SCOPE_AGENT);
        if (m == tgt2 - 1u)
          __hip_atomic_store(qf, (unsigned)(t + 1),
                             __ATOMIC_RELAXED, __HIP_MEMORY_SCOPE_AGENT);
      }
    }

    // ---- spin-window work: h + H store (not needed by consumers) ----
    {
      float po = g.w + b2f((unsigned short)xw[3]);
      float h  = sigmoidf_(po) * tanhf_(c2);
      unsigned hl = f2b(h);
      unsigned hh = __shfl_down(hl, 1);
      if (!(lane & 1))
        *(hp + (size_t)t * 512) = hl | (hh << 16);   // u32 ptr: row stride 512 u32
    }
    // prefetch next step's XW row (read-only stream)
    if (t < 255) xw = *(const u16x4*)(xwp + (size_t)(t + 1) * 4096);

    if (tid == 0) {
      while (__hip_atomic_load(qf, __ATOMIC_RELAXED, __HIP_MEMORY_SCOPE_AGENT)
             < (unsigned)(t + 1))
        __builtin_amdgcn_s_sleep(1);
    }
    __syncthreads();   // release
  }

  // final f32 cell state from registers (kernel-end flush covers it)
  cellOut[(size_t)browg * 1024 + cs * 32 + ecol] = cf;
}

// ---------- launcher ----------
extern "C" void kernel_launch(void* const* d_in, const int* in_sizes, int n_in,
                              void* d_out, int out_size, void* d_ws, size_t ws_size,
                              hipStream_t stream) {
  const float* x   = (const float*)d_in[0];
  const float* Wf  = (const float*)d_in[1];
  const float* bfv = (const float*)d_in[2];
  const float* Wi1 = (const float*)d_in[3];
  const float* bi1 = (const float*)d_in[4];
  const float* Wi2 = (const float*)d_in[5];
  const float* bi2 = (const float*)d_in[6];
  const float* Wo  = (const float*)d_in[7];
  const float* bo  = (const float*)d_in[8];
  const float* Wc  = (const float*)d_in[9];
  const float* bc  = (const float*)d_in[10];
  float* out = (float*)d_out;

  if (ws_size < WS_NEEDED) return;  // visible failure instead of corruption

  char* ws = (char*)d_ws;
  unsigned short* xb      = (unsigned short*)(ws + OFF_XB);
  unsigned short* WhT     = (unsigned short*)(ws + OFF_WHT);
  unsigned short* WxT     = (unsigned short*)(ws + OFF_WXT);
  unsigned short* WcT     = (unsigned short*)(ws + OFF_WCT);
  float*          biasAll = (float*)(ws + OFF_BIAS);
  unsigned short* XW      = (unsigned short*)(ws + OFF_XW);
  unsigned short* H       = (unsigned short*)(ws + OFF_H);
  unsigned short* cB0     = (unsigned short*)(ws + OFF_CB);
  unsigned short* cB1     = (unsigned short*)(ws + OFF_CB + (size_t)128 * 1024 * 2);
  unsigned*       barLn   = (unsigned*)(ws + OFF_BAR);
  float*          cellOut = out + (size_t)32768 * 1024;

  hipMemsetAsync(cB0, 0, (size_t)128 * 1024 * 2, stream);
  hipMemsetAsync(barLn, 0, 32768, stream);    // reset barrier lines EVERY launch

  cvt_x_kernel <<<32768, 256, 0, stream>>>(x, xb);
  cvt_w_kernel <<< 1024, 256, 0, stream>>>(Wf, Wi1, Wi2, Wo, WhT, WxT);
  bias_kernel  <<<   16, 256, 0, stream>>>(bfv, bi1, bi2, bo, biasAll);
  cvt_wc_kernel<<< 4096, 256, 0, stream>>>(Wc, WcT);

  // XW = x @ Wx_all + biases   (M=32768, N=4096, K=1024), bf16 out, 256^2 tiles
  gemm_bt<false><<<dim3(16, 128), 512, 0, stream>>>(xb, WxT, biasAll, XW, 32768, 4096, 1024);

  // persistent recurrence: 256 WGs x 512 threads (proven envelope), cooperative
  {
    void* args[] = { (void*)&WhT, (void*)&XW, (void*)&H,
                     (void*)&cB0, (void*)&cB1, (void*)&cellOut, (void*)&barLn };
    hipLaunchCooperativeKernel(lstm_persist, dim3(256), dim3(512), args, 0u, stream);
  }

  // output_sequence = h @ Wc + bc  (M=32768, N=1024, K=1024), f32 out
  gemm_bt<true><<<dim3(4, 128), 512, 0, stream>>>(H, WcT, bc, out, 32768, 1024, 1024);
}

// Round 17
// 1335.178 us; speedup vs baseline: 1.0347x; 1.0111x over previous
//
#include <hip/hip_runtime.h>
#include <cstdint>
#include <cstddef>

#define DEVINL __device__ __forceinline__

typedef __attribute__((ext_vector_type(8))) short bf16x8;
typedef __attribute__((ext_vector_type(4))) float f32x4;
typedef __attribute__((ext_vector_type(4))) unsigned short u16x4;
typedef __attribute__((ext_vector_type(4))) unsigned int u32x4;

// ---------- workspace layout ----------
static constexpr size_t OFF_XB   = 0;                              // x bf16 [32768][1024]
static constexpr size_t OFF_WHT  = OFF_XB  + (size_t)32768*1024*2; // Wh^T bf16 [4096][1024]
static constexpr size_t OFF_WXT  = OFF_WHT + (size_t)4096*1024*2;  // Wx^T bf16 [4096][1024]
static constexpr size_t OFF_WCT  = OFF_WXT + (size_t)4096*1024*2;  // Wc^T bf16 [1024][1024]
static constexpr size_t OFF_BIAS = OFF_WCT + (size_t)1024*1024*2;  // bias_all f32 [4096]
static constexpr size_t OFF_XW   = OFF_BIAS + 4096*4;              // XW bf16 [32768][4096]
static constexpr size_t OFF_H    = OFF_XW  + (size_t)32768*4096*2; // h bf16 [32768][1024]
static constexpr size_t OFF_CB   = OFF_H   + (size_t)32768*1024*2; // cell bf16 x2 [128][1024]
static constexpr size_t OFF_BAR  = OFF_CB  + (size_t)2*128*1024*2; // barrier lines, 32 KB
static constexpr size_t WS_NEEDED = OFF_BAR + 32768;

// ---------- helpers ----------
DEVINL unsigned short f2b(float f) {
  union { float f; unsigned u; } v; v.f = f;
  unsigned r = (v.u + 0x7FFFu + ((v.u >> 16) & 1u)) >> 16;  // RNE
  return (unsigned short)r;
}
DEVINL float b2f(unsigned short h) {
  union { unsigned u; float f; } v; v.u = ((unsigned)h) << 16;
  return v.f;
}
DEVINL float sigmoidf_(float x) { return 1.0f / (1.0f + __expf(-x)); }
DEVINL float tanhf_(float x) { float e = __expf(2.0f * x); return 1.0f - 2.0f / (e + 1.0f); }
DEVINL f32x4 MFMA(bf16x8 a, bf16x8 b, f32x4 c) {
  return __builtin_amdgcn_mfma_f32_16x16x32_bf16(a, b, c, 0, 0, 0);
}
DEVINL void gload16(const void* g, void* l) {
  __builtin_amdgcn_global_load_lds(
      (const __attribute__((address_space(1))) void*)g,
      (__attribute__((address_space(3))) void*)l, 16, 0, 0);
}

// ---------- conversions ----------
__global__ void cvt_x_kernel(const float* __restrict__ x, unsigned short* __restrict__ xb) {
  size_t i = ((size_t)blockIdx.x * 256 + threadIdx.x) * 4;
  float4 v = *(const float4*)(x + i);
  u16x4 o; o.x = f2b(v.x); o.y = f2b(v.y); o.z = f2b(v.z); o.w = f2b(v.w);
  *(u16x4*)(xb + i) = o;
}

// coalesced transpose-convert via 64x64 LDS tile (proven r8)
__global__ __launch_bounds__(256)
void cvt_w_kernel(const float* __restrict__ Wf, const float* __restrict__ Wi1,
                  const float* __restrict__ Wi2, const float* __restrict__ Wo,
                  unsigned short* __restrict__ WhT, unsigned short* __restrict__ WxT) {
  __shared__ float tile[64][65];
  const int bid = blockIdx.x;          // 16 jt x 16 kt x 4 g = 1024 blocks
  const int g  = bid & 3;
  const int kt = (bid >> 2) & 15;
  const int jt = bid >> 6;
  const float* W = (g == 0) ? Wf : (g == 1) ? Wi1 : (g == 2) ? Wi2 : Wo;
  const int tid = threadIdx.x;
  const int jj  = tid & 63;
  const int kr  = tid >> 6;            // 0..3

  for (int h = 0; h < 2; ++h) {
    const float* Wb = W + (size_t)(h ? 1024 : 0) * 1024;
#pragma unroll
    for (int i = 0; i < 16; ++i) {
      int kl = i * 4 + kr;
      tile[kl][jj] = Wb[(size_t)(kt * 64 + kl) * 1024 + jt * 64 + jj];
    }
    __syncthreads();
    unsigned short* Out = h ? WxT : WhT;
    unsigned short* op  = Out + (size_t)(4 * (jt * 64 + jj) + g) * 1024 + kt * 64 + kr * 16;
#pragma unroll
    for (int q = 0; q < 4; ++q) {
      u16x4 v;
#pragma unroll
      for (int e = 0; e < 4; ++e)
        ((unsigned short*)&v)[e] = f2b(tile[kr * 16 + q * 4 + e][jj]);
      *(u16x4*)(op + q * 4) = v;
    }
    __syncthreads();
  }
}

__global__ void bias_kernel(const float* __restrict__ bf_, const float* __restrict__ bi1,
                            const float* __restrict__ bi2, const float* __restrict__ bo,
                            float* __restrict__ biasAll) {
  int gc = blockIdx.x * 256 + threadIdx.x;   // 4096
  int j = gc >> 2, g = gc & 3;
  const float* bb = (g == 0) ? bf_ : (g == 1) ? bi1 : (g == 2) ? bi2 : bo;
  biasAll[gc] = bb[j];
}

__global__ void cvt_wc_kernel(const float* __restrict__ Wc, unsigned short* __restrict__ WcT) {
  int idx = blockIdx.x * 256 + threadIdx.x;   // 1024*1024 total
  int k = idx & 1023, n = idx >> 10;
  WcT[idx] = f2b(Wc[(size_t)k * 1024 + n]);
}

// ---------- 256x256 pipelined bf16 GEMM (r12-proven) ----------
template<bool OUT_F32>
__global__ __launch_bounds__(512, 2)
void gemm_bt(const unsigned short* __restrict__ A,
             const unsigned short* __restrict__ Bt,
             const float* __restrict__ bias,
             void* __restrict__ C,
             int M, int N, int K) {
  __shared__ char sT[4][32768];        // per buf: A[256][32] @0, B[256][32] @16384
  const int tid  = threadIdx.x;
  const int lane = tid & 63;
  const int wid  = tid >> 6;
  const int wm   = (wid >> 2) * 128;
  const int wn   = (wid & 3) * 64;

  const int nwg = gridDim.x * gridDim.y;
  const int lin = blockIdx.y * gridDim.x + blockIdx.x;
  const int cpx = nwg >> 3;
  const int swz = (lin & 7) * cpx + (lin >> 3);
  const int m0  = (swz / gridDim.x) * 256;
  const int n0  = (swz % gridDim.x) * 256;

  const int nt = K >> 5;

  f32x4 acc[8][4];
#pragma unroll
  for (int i = 0; i < 8; ++i)
#pragma unroll
    for (int j = 0; j < 4; ++j) acc[i][j] = (f32x4){0.f, 0.f, 0.f, 0.f};

  auto stageA = [&](int kt, int buf) {
#pragma unroll
    for (int l = 0; l < 2; ++l) {
      int s = l * 512 + tid;
      int r = s >> 2, c = s & 3;
      int cg = c ^ ((r >> 1) & 3);
      gload16(A + (size_t)(m0 + r) * K + kt * 32 + cg * 8, sT[buf] + s * 16);
    }
  };
  auto stageB = [&](int kt, int buf) {
#pragma unroll
    for (int l = 0; l < 2; ++l) {
      int s = l * 512 + tid;
      int r = s >> 2, c = s & 3;
      int cg = c ^ ((r >> 1) & 3);
      gload16(Bt + (size_t)(n0 + r) * K + kt * 32 + cg * 8, sT[buf] + 16384 + s * 16);
    }
  };

  stageA(0, 0); stageB(0, 0);
  stageA(1, 1); stageB(1, 1);
  stageA(2, 2); stageB(2, 2);
  asm volatile("s_waitcnt vmcnt(8)" ::: "memory");
  __builtin_amdgcn_s_barrier();

  const int ch = lane >> 4;

#pragma unroll 1
  for (int g = 0; g < nt; ++g) {
    const int rb = g & 3;
    const char* ab = sT[rb];
    const char* bb = sT[rb] + 16384;

    bf16x8 bv[4], av[4];
#pragma unroll
    for (int ni = 0; ni < 4; ++ni) {
      int col = wn + ni * 16 + (lane & 15);
      bv[ni] = *(const bf16x8*)(bb + col * 64 + ((ch ^ ((col >> 1) & 3)) << 4));
    }
#pragma unroll
    for (int mi = 0; mi < 4; ++mi) {
      int row = wm + mi * 16 + (lane & 15);
      av[mi] = *(const bf16x8*)(ab + row * 64 + ((ch ^ ((row >> 1) & 3)) << 4));
    }
    if (g + 3 < nt) stageA(g + 3, (g + 3) & 3);
    __builtin_amdgcn_s_barrier();
    __builtin_amdgcn_s_setprio(1);
#pragma unroll
    for (int mi = 0; mi < 4; ++mi)
#pragma unroll
      for (int ni = 0; ni < 4; ++ni)
        acc[mi][ni] = MFMA(av[mi], bv[ni], acc[mi][ni]);
    __builtin_amdgcn_s_setprio(0);
    __builtin_amdgcn_s_barrier();

#pragma unroll
    for (int mi = 0; mi < 4; ++mi) {
      int row = wm + 64 + mi * 16 + (lane & 15);
      av[mi] = *(const bf16x8*)(ab + row * 64 + ((ch ^ ((row >> 1) & 3)) << 4));
    }
    if (g + 3 < nt) stageB(g + 3, (g + 3) & 3);
    __builtin_amdgcn_s_barrier();
    __builtin_amdgcn_s_setprio(1);
#pragma unroll
    for (int mi = 0; mi < 4; ++mi)
#pragma unroll
      for (int ni = 0; ni < 4; ++ni)
        acc[mi + 4][ni] = MFMA(av[mi], bv[ni], acc[mi + 4][ni]);
    __builtin_amdgcn_s_setprio(0);

    if (g <= nt - 4)      asm volatile("s_waitcnt vmcnt(8)" ::: "memory");
    else if (g == nt - 3) asm volatile("s_waitcnt vmcnt(4)" ::: "memory");
    else if (g == nt - 2) asm volatile("s_waitcnt vmcnt(0)" ::: "memory");
    __builtin_amdgcn_s_barrier();
  }

#pragma unroll
  for (int mi = 0; mi < 8; ++mi)
#pragma unroll
    for (int ni = 0; ni < 4; ++ni)
#pragma unroll
      for (int r = 0; r < 4; ++r) {
        int row = m0 + wm + mi * 16 + (lane >> 4) * 4 + r;
        int col = n0 + wn + ni * 16 + (lane & 15);
        float v = acc[mi][ni][r] + bias[col];
        if (OUT_F32) ((float*)C)[(size_t)row * N + col] = v;
        else ((unsigned short*)C)[(size_t)row * N + col] = f2b(v);
      }
}

// ---------- persistent recurrence (r14-exact: best measured, 924us) ----------
// 256 WGs x 512 thr, 8 row-groups x 32 WGs; MALL protocol (relaxed agent-
// atomic coalesced cell stores, sc0|sc1 asm cell loads, H plain cached);
// 2-level tree barrier (tid0 only); elementwise on all 512 threads (1 cell);
// h + H store deferred into the spin window; XW row prefetched.
// r15 transpose (store scatter) and r16 4-chain split (neutral) reverted.
__global__ __launch_bounds__(512, 2)
void lstm_persist(const unsigned short* __restrict__ WhT,  // [4096][1024] bf16
                  const unsigned short* __restrict__ XW,   // [32768][4096] bf16
                  unsigned short* __restrict__ H,          // [32768][1024] bf16
                  unsigned short* __restrict__ cB0,        // [128][1024] bf16
                  unsigned short* __restrict__ cB1,
                  float* __restrict__ cellOut,             // [128][1024] f32
                  unsigned* __restrict__ bar) {
  __shared__ __align__(16) char  sA[16 * 2064];   // 33 KB A-tile, padded stride
  __shared__ __align__(16) float sP[16 * 132];    // 8.4 KB preact redistribute

  const int tid  = threadIdx.x;
  const int lane = tid & 63;
  const int nh   = tid >> 6;       // wave id = n-tile 0..7
  const int wgid = blockIdx.x;
  const int mq   = wgid & 7;       // row-group (16 rows)
  const int cs   = wgid >> 3;      // col slice 0..31 (128 gate-cols)
  const int sg   = cs >> 2;        // subgroup 0..7 (4 WGs each)

  // barrier lines (256B spacing): qc 0..511, qf 512..1023, gcnt 1024..5119
  unsigned* qc   = bar + mq * 64;
  unsigned* qf   = bar + 512 + mq * 64;
  unsigned* gcnt = bar + 1024 + (mq * 8 + sg) * 64;

  const int r0 = lane & 15;        // row within m-tile / col within n-tile
  const int ch = lane >> 4;        // 16B chunk id within K-slice

  // ---- Wh fragments in registers: volatile loads (non-remat), 128 regs ----
  bf16x8 bfr[32];
  {
    const unsigned short* bp = WhT + (size_t)(cs * 128 + nh * 16 + r0) * 1024 + ch * 8;
#pragma unroll
    for (int ks = 0; ks < 32; ++ks)
      bfr[ks] = *(const volatile bf16x8*)(bp + ks * 32);
  }

  // ---- per-thread cell ownership: ALL 512 threads, 1 cell each ----
  const int erow  = tid >> 5;            // 0..15 (row within group)
  const int ecol  = tid & 31;            // cell col within slice
  const int browg = mq * 16 + erow;      // global batch row
  float cf = 0.f;

  const unsigned short* xwp = XW + (size_t)browg * 256 * 4096 + cs * 128 + ecol * 4;
  // u32 store pointers (even lanes store cols {ecol, ecol+1})
  unsigned* c0p = (unsigned*)(cB0 + (size_t)browg * 1024 + cs * 32 + ecol);
  unsigned* c1p = (unsigned*)(cB1 + (size_t)browg * 1024 + cs * 32 + ecol);
  unsigned* hp  = (unsigned*)(H + (size_t)browg * 256 * 1024 + cs * 32 + ecol);

  // staging geometry: thread covers rows {4it+strow}, 16B chunk stcc
  const int strow = tid >> 7;            // 0..3
  const int stcc  = tid & 127;           // 0..127

  // prologue: xw for t=0
  u16x4 xw = *(const u16x4*)(xwp);

  for (int t = 0; t < 256; ++t) {
    const unsigned short* cinq = ((t & 1) ? cB1 : cB0) + (size_t)mq * 16 * 1024;

    // ---- stage A-tile [16][1024] bf16: coherent loads -> regs -> LDS ----
    u32x4 st[4];
#pragma unroll
    for (int it = 0; it < 4; ++it) {
      const void* p = cinq + (size_t)(it * 4 + strow) * 1024 + stcc * 8;
      asm volatile("global_load_dwordx4 %0, %1, off sc0 sc1"
                   : "=&v"(st[it]) : "v"(p) : "memory");
    }
    asm volatile("s_waitcnt vmcnt(0)" ::: "memory");
    __builtin_amdgcn_sched_barrier(0);
#pragma unroll
    for (int it = 0; it < 4; ++it) {
      int r = it * 4 + strow;
      *(u32x4*)&sA[r * 2064 + stcc * 16] = st[it];
    }
    __syncthreads();   // sA ready

    // ---- GEMM: one 16x16 tile per wave, K=1024; A LDS, B regs ----
    f32x4 acc = (f32x4){0.f, 0.f, 0.f, 0.f};
#pragma unroll
    for (int ks = 0; ks < 32; ++ks) {
      bf16x8 a0 = *(const bf16x8*)&sA[r0 * 2064 + (ch + ks * 4) * 16];
      acc = MFMA(a0, bfr[ks], acc);
    }

    // ---- redistribute preacts via LDS ----
#pragma unroll
    for (int rr = 0; rr < 4; ++rr)
      sP[(ch * 4 + rr) * 132 + nh * 16 + r0] = acc[rr];
    __syncthreads();   // sP ready

    // ---- critical-path elementwise: c2 only (3 transcendentals) ----
    float4 g = *(const float4*)&sP[erow * 132 + ecol * 4];
    float pf = g.x + b2f((unsigned short)xw[0]);
    float pi = g.y + b2f((unsigned short)xw[1]);
    float pg = g.z + b2f((unsigned short)xw[2]);
    float f  = sigmoidf_(pf), i1 = sigmoidf_(pi), gg = tanhf_(pg);
    float c2 = cf * f + i1 * gg; cf = c2;

    // cell: pack adjacent cols via shfl, even lanes agent-store u32 to MALL
    unsigned cl = f2b(c2);
    unsigned chi = __shfl_down(cl, 1);
    if (!(lane & 1))
      __hip_atomic_store((t & 1) ? c0p : c1p, cl | (chi << 16),
                         __ATOMIC_RELAXED, __HIP_MEMORY_SCOPE_AGENT);

    // ---- drain: all cell stores at MALL, then signal ----
    __syncthreads();
    if (tid == 0) {
      unsigned tgt1 = 4u * (unsigned)(t + 1);
      unsigned tgt2 = 8u * (unsigned)(t + 1);
      unsigned n = __hip_atomic_fetch_add(gcnt, 1u, __ATOMIC_RELAXED,
                                          __HIP_MEMORY_SCOPE_AGENT);
      if (n == tgt1 - 1u) {
        unsigned m = __hip_atomic_fetch_add(qc, 1u, __ATOMIC_RELAXED,
                                            __HIP_MEMORY_SCOPE_AGENT);
        if (m == tgt2 - 1u)
          __hip_atomic_store(qf, (unsigned)(t + 1),
                             __ATOMIC_RELAXED, __HIP_MEMORY_SCOPE_AGENT);
      }
    }

    // ---- spin-window work: h + H store (not needed by consumers) ----
    {
      float po = g.w + b2f((unsigned short)xw[3]);
      float h  = sigmoidf_(po) * tanhf_(c2);
      unsigned hl = f2b(h);
      unsigned hh = __shfl_down(hl, 1);
      if (!(lane & 1))
        *(hp + (size_t)t * 512) = hl | (hh << 16);   // u32 ptr: row stride 512 u32
    }
    // prefetch next step's XW row (read-only stream)
    if (t < 255) xw = *(const u16x4*)(xwp + (size_t)(t + 1) * 4096);

    if (tid == 0) {
      while (__hip_atomic_load(qf, __ATOMIC_RELAXED, __HIP_MEMORY_SCOPE_AGENT)
             < (unsigned)(t + 1))
        __builtin_amdgcn_s_sleep(1);
    }
    __syncthreads();   // release
  }

  // final f32 cell state from registers (kernel-end flush covers it)
  cellOut[(size_t)browg * 1024 + cs * 32 + ecol] = cf;
}

// ---------- launcher ----------
extern "C" void kernel_launch(void* const* d_in, const int* in_sizes, int n_in,
                              void* d_out, int out_size, void* d_ws, size_t ws_size,
                              hipStream_t stream) {
  const float* x   = (const float*)d_in[0];
  const float* Wf  = (const float*)d_in[1];
  const float* bfv = (const float*)d_in[2];
  const float* Wi1 = (const float*)d_in[3];
  const float* bi1 = (const float*)d_in[4];
  const float* Wi2 = (const float*)d_in[5];
  const float* bi2 = (const float*)d_in[6];
  const float* Wo  = (const float*)d_in[7];
  const float* bo  = (const float*)d_in[8];
  const float* Wc  = (const float*)d_in[9];
  const float* bc  = (const float*)d_in[10];
  float* out = (float*)d_out;

  if (ws_size < WS_NEEDED) return;  // visible failure instead of corruption

  char* ws = (char*)d_ws;
  unsigned short* xb      = (unsigned short*)(ws + OFF_XB);
  unsigned short* WhT     = (unsigned short*)(ws + OFF_WHT);
  unsigned short* WxT     = (unsigned short*)(ws + OFF_WXT);
  unsigned short* WcT     = (unsigned short*)(ws + OFF_WCT);
  float*          biasAll = (float*)(ws + OFF_BIAS);
  unsigned short* XW      = (unsigned short*)(ws + OFF_XW);
  unsigned short* H       = (unsigned short*)(ws + OFF_H);
  unsigned short* cB0     = (unsigned short*)(ws + OFF_CB);
  unsigned short* cB1     = (unsigned short*)(ws + OFF_CB + (size_t)128 * 1024 * 2);
  unsigned*       barLn   = (unsigned*)(ws + OFF_BAR);
  float*          cellOut = out + (size_t)32768 * 1024;

  hipMemsetAsync(cB0, 0, (size_t)128 * 1024 * 2, stream);
  hipMemsetAsync(barLn, 0, 32768, stream);    // reset barrier lines EVERY launch

  cvt_x_kernel <<<32768, 256, 0, stream>>>(x, xb);
  cvt_w_kernel <<< 1024, 256, 0, stream>>>(Wf, Wi1, Wi2, Wo, WhT, WxT);
  bias_kernel  <<<   16, 256, 0, stream>>>(bfv, bi1, bi2, bo, biasAll);
  cvt_wc_kernel<<< 4096, 256, 0, stream>>>(Wc, WcT);

  // XW = x @ Wx_all + biases   (M=32768, N=4096, K=1024), bf16 out, 256^2 tiles
  gemm_bt<false><<<dim3(16, 128), 512, 0, stream>>>(xb, WxT, biasAll, XW, 32768, 4096, 1024);

  // persistent recurrence: 256 WGs x 512 threads (proven envelope), cooperative
  {
    void* args[] = { (void*)&WhT, (void*)&XW, (void*)&H,
                     (void*)&cB0, (void*)&cB1, (void*)&cellOut, (void*)&barLn };
    hipLaunchCooperativeKernel(lstm_persist, dim3(256), dim3(512), args, 0u, stream);
  }

  // output_sequence = h @ Wc + bc  (M=32768, N=1024, K=1024), f32 out
  gemm_bt<true><<<dim3(4, 128), 512, 0, stream>>>(H, WcT, bc, out, 32768, 1024, 1024);
}